// Round 7
// baseline (327.501 us; speedup 1.0000x reference)
//
#include <hip/hip_runtime.h>
#include <hip/hip_bf16.h>

// SwiGLU MLP: out = (silu(x@wg^T * S) * (x@wu^T * S)) @ wd^T * S,  S = 1/127
// Round 7: G1 reverted to the round-4 8-phase code (best measured, 119 us),
// sole template instantiation. G2 rebuilt: 2-phase 128^2 (round-2's measured
// 837 TF structure), split-K=2 with f32 atomicAdd epilogue onto memset-zeroed
// d_out -- no partials buffer, no reduce kernel, ~100 MB less HBM traffic.
// G2 XCD map: each XCD owns a disjoint 1024-row h band (h fetched once).

typedef __attribute__((ext_vector_type(8))) __bf16 bf16x8;
typedef __attribute__((ext_vector_type(4))) float f32x4;

static constexpr float QS = 1.0f / 127.0f;

#define BAR()    asm volatile("s_barrier" ::: "memory")
#define VMCNT4() asm volatile("s_waitcnt vmcnt(4)" ::: "memory")
#define VMCNT0() asm volatile("s_waitcnt vmcnt(0)" ::: "memory")
#define LGKM8()  asm volatile("s_waitcnt lgkmcnt(8)" ::: "memory")
#define PRIO1()  __builtin_amdgcn_s_setprio(1)
#define PRIO0()  __builtin_amdgcn_s_setprio(0)
#define SB0()    __builtin_amdgcn_sched_barrier(0)

__device__ __forceinline__ void gload_lds16(const void* g, void* l) {
  __builtin_amdgcn_global_load_lds(
      (const __attribute__((address_space(1))) void*)g,
      (__attribute__((address_space(3))) void*)l,
      16, 0, 0);
}

// ---------------- conversion kernels ----------------

__global__ __launch_bounds__(256) void k_conv_x(const float* __restrict__ x,
                                                __bf16* __restrict__ xb, int n8) {
  int t = blockIdx.x * 256 + threadIdx.x;
  if (t >= n8) return;
  const float4* p = (const float4*)(x + (size_t)t * 8);
  float4 a = p[0], b = p[1];
  bf16x8 o;
  o[0] = (__bf16)a.x; o[1] = (__bf16)a.y; o[2] = (__bf16)a.z; o[3] = (__bf16)a.w;
  o[4] = (__bf16)b.x; o[5] = (__bf16)b.y; o[6] = (__bf16)b.z; o[7] = (__bf16)b.w;
  *(bf16x8*)(xb + (size_t)t * 8) = o;
}

__global__ __launch_bounds__(256) void k_conv_w1(const int* __restrict__ wg,
                                                 const int* __restrict__ wu,
                                                 __bf16* __restrict__ w1) {
  int t = blockIdx.x * 256 + threadIdx.x;
  int c8 = t & 127;
  int v = t >> 7;
  int bb = v >> 5, tt = v & 31;
  const int* src = (tt < 16) ? (wg + (size_t)(bb * 16 + tt) * 1024)
                             : (wu + (size_t)(bb * 16 + (tt & 15)) * 1024);
  const int4* p = (const int4*)(src + c8 * 8);
  int4 a = p[0], b = p[1];
  bf16x8 o;
  o[0] = (__bf16)(float)a.x; o[1] = (__bf16)(float)a.y;
  o[2] = (__bf16)(float)a.z; o[3] = (__bf16)(float)a.w;
  o[4] = (__bf16)(float)b.x; o[5] = (__bf16)(float)b.y;
  o[6] = (__bf16)(float)b.z; o[7] = (__bf16)(float)b.w;
  *(bf16x8*)(w1 + (size_t)v * 1024 + c8 * 8) = o;
}

__global__ __launch_bounds__(256) void k_conv_wd(const int* __restrict__ wdn,
                                                 __bf16* __restrict__ wdb, int n8) {
  int t = blockIdx.x * 256 + threadIdx.x;
  if (t >= n8) return;
  const int4* p = (const int4*)(wdn + (size_t)t * 8);
  int4 a = p[0], b = p[1];
  bf16x8 o;
  o[0] = (__bf16)(float)a.x; o[1] = (__bf16)(float)a.y;
  o[2] = (__bf16)(float)a.z; o[3] = (__bf16)(float)a.w;
  o[4] = (__bf16)(float)b.x; o[5] = (__bf16)(float)b.y;
  o[6] = (__bf16)(float)b.z; o[7] = (__bf16)(float)b.w;
  *(bf16x8*)(wdb + (size_t)t * 8) = o;
}

// -------- G1: 256x256 8-phase GEMM, SwiGLU fused (round-4 code, exact) ------

#define MFMA16(MG, NG)                                                         \
  _Pragma("unroll") for (int mi = 0; mi < 4; ++mi) {                           \
    _Pragma("unroll") for (int nj = 0; nj < 2; ++nj) {                         \
      acc[(MG)*4 + mi][(NG)*2 + nj] = __builtin_amdgcn_mfma_f32_16x16x32_bf16( \
          af[mi][0], bf[NG][nj][0], acc[(MG)*4 + mi][(NG)*2 + nj], 0, 0, 0);   \
      acc[(MG)*4 + mi][(NG)*2 + nj] = __builtin_amdgcn_mfma_f32_16x16x32_bf16( \
          af[mi][1], bf[NG][nj][1], acc[(MG)*4 + mi][(NG)*2 + nj], 0, 0, 0);   \
    }                                                                          \
  }

#define LDAF(MG)                                                               \
  _Pragma("unroll") for (int mi = 0; mi < 4; ++mi) {                           \
    af[mi][0] = *(const bf16x8*)(aL + ((MG)*64 + mi * 16 + r16) * 128 + s0);   \
    af[mi][1] = *(const bf16x8*)(aL + ((MG)*64 + mi * 16 + r16) * 128 + s1);   \
  }

#define LDBF(NG)                                                               \
  _Pragma("unroll") for (int nj = 0; nj < 2; ++nj) {                           \
    bf[NG][nj][0] = *(const bf16x8*)(bL + (bro + (NG)*32 + nj * 16) * 128 + s0); \
    bf[NG][nj][1] = *(const bf16x8*)(bL + (bro + (NG)*32 + nj * 16) * 128 + s1); \
  }

__global__ __launch_bounds__(512, 2) void k_gemm1_8p(const __bf16* __restrict__ A,
                                                     const __bf16* __restrict__ Bp,
                                                     __bf16* __restrict__ Out) {
  constexpr int LDAK = 1024, NT = 16, LDO = 3072;
  const int row0 = blockIdx.y * 256, col0 = blockIdx.x * 256;
  const int kz = 0;
  __shared__ __bf16 sA[2][2][128][64];   // [buf][half][row][k]
  __shared__ __bf16 sB[2][2][128][64];
  const int tid = threadIdx.x;           // 0..511
  const int lane = tid & 63;
  const int wid = tid >> 6;              // 0..7
  const int wm = wid >> 2, wn = wid & 3; // 2 x 4 waves
  const int r16 = lane & 15;
  const int kq = lane >> 4;

  auto STG = [&](__bf16* dst, const __bf16* src, int rbase, int kt) {
    int r0 = tid >> 3;
    int c0 = (tid & 7) ^ (r0 & 7);               // inverse T2 swizzle on src
    int r1 = 64 + r0;
    gload_lds16(src + (size_t)(rbase + r0) * LDAK + kt * 64 + c0 * 8,
                dst + tid * 8);
    gload_lds16(src + (size_t)(rbase + r1) * LDAK + kt * 64 + c0 * 8,
                dst + (512 + tid) * 8);
  };

  f32x4 acc[8][4] = {};

  // prologue: T0 complete + T1:{Bh0, Ah0}
  STG(&sA[0][0][0][0], A, row0, kz);
  STG(&sB[0][0][0][0], Bp, col0, kz);
  STG(&sA[0][1][0][0], A, row0 + 128, kz);
  STG(&sB[0][1][0][0], Bp, col0 + 128, kz);
  const int kt1 = kz + 1;
  STG(&sB[1][0][0][0], Bp, col0, kt1);
  STG(&sA[1][0][0][0], A, row0, kt1);
  VMCNT4();   // T0 landed; T1:{Bh0,Ah0} in flight
  BAR();

  for (int t = 0; t < NT; ++t) {
    const int c = t & 1;
    const char* aL = (const char*)&sA[c][wm][0][0];
    const char* bL = (const char*)&sB[c][wn >> 1][0][0];
    const int bro = (wn & 1) * 64 + r16;
    const int s0 = ((kq) ^ (r16 & 7)) << 4;
    const int s1 = ((4 + kq) ^ (r16 & 7)) << 4;
    const int k1 = kz + (t + 1 < NT ? t + 1 : NT - 1);
    const int k2 = kz + (t + 2 < NT ? t + 2 : NT - 1);
    bf16x8 af[4][2], bf[2][2][2];

    // ---- phase 1: q(0,0)
    LDAF(0);
    LDBF(0);
    LGKM8();                                      // 12 reads issued; pre-drain
    STG(&sA[c ^ 1][1][0][0], A, row0 + 128, k1);  // T+1 Ah1 (idle buf)
    BAR();
    PRIO1(); MFMA16(0, 0); PRIO0();
    BAR();
    // ---- phase 2: q(0,1)
    LDBF(1);
    STG(&sB[c ^ 1][1][0][0], Bp, col0 + 128, k1); // T+1 Bh1 (idle buf)
    BAR();
    PRIO1(); MFMA16(0, 1); PRIO0();
    BAR();
    // ---- phase 3: q(1,0)  — B regions of buf c dead (last read ph2)
    LDAF(1);
    STG(&sB[c][0][0][0], Bp, col0, k2);           // T+2 Bh0
    BAR();
    PRIO1(); MFMA16(1, 0); PRIO0();
    BAR();
    // ---- phase 4: q(1,1)  — A regions of buf c dead (last read ph3)
    STG(&sA[c][0][0][0], A, row0, k2);            // T+2 Ah0
    BAR();
    PRIO1(); MFMA16(1, 1); PRIO0();
    VMCNT4();   // tile T+1 fully landed; 2 half-tiles stay in flight
    BAR();
  }

  // SwiGLU epilogue: B cols are (gate|up) 16-blocks -> gate/up of one h column
  // sit in adjacent j-fragments of the SAME lane.
  __bf16* hout = Out;
  const int hbase = (col0 + wn * 64) >> 1;
#pragma unroll
  for (int i = 0; i < 8; ++i) {
#pragma unroll
    for (int p = 0; p < 2; ++p) {
#pragma unroll
      for (int rr = 0; rr < 4; ++rr) {
        int row = row0 + wm * 128 + i * 16 + kq * 4 + rr;
        float g = acc[i][2 * p][rr] * QS;
        float u = acc[i][2 * p + 1][rr] * QS;
        float hv = (g / (1.0f + __expf(-g))) * u;
        hout[(size_t)row * LDO + hbase + p * 16 + r16] = (__bf16)hv;
      }
    }
  }
  VMCNT0();   // drain dead tail stages before LDS handoff to next block
}

// -------- G2: 2-phase 128^2, split-K=2, atomicAdd epilogue ------------------
// [8192,3072] x [1024,3072]^T -> += out f32 [8192,1024] (d_out pre-zeroed).
// 1024 blocks, 4/CU. XCD map: xcd=b&7 owns rows [xcd*1024, xcd*1024+1024)
// (h fetched once); within XCD: z slowest, then y, x fastest.
__global__ __launch_bounds__(256) void k_gemm2a(const __bf16* __restrict__ H,
                                                const __bf16* __restrict__ Bw,
                                                float* __restrict__ out) {
  __shared__ __bf16 sA[128][64];
  __shared__ __bf16 sB[128][64];
  const int b = blockIdx.x;
  const int xcd = b & 7, ii = b >> 3;          // ii 0..127
  const int z = ii >> 6;                       // 0..1 (slowest)
  const int rem = ii & 63;
  const int yy = rem >> 3, xx = rem & 7;       // y 0..7, x 0..7
  const int row0 = (xcd * 8 + yy) * 128, col0 = xx * 128;
  const int kz = z * 24;

  const int tid = threadIdx.x;
  const int lane = tid & 63;
  const int wid = tid >> 6;
  const int wm = wid >> 1, wn = wid & 1;
  const int r16 = lane & 15;
  const int kq = lane >> 4;

  f32x4 acc[4][4] = {};

  for (int kt = kz; kt < kz + 24; ++kt) {
    __syncthreads();
#pragma unroll
    for (int it = 0; it < 4; ++it) {
      int chunk = it * 256 + tid;  // 0..1023 chunks of 16B
      int r = chunk >> 3, kc = chunk & 7;
      int kcs = kc ^ (r & 7);  // inverse swizzle on the global source
      gload_lds16(H + (size_t)(row0 + r) * 3072 + kt * 64 + kcs * 8,
                  ((__bf16*)sA) + chunk * 8);
      gload_lds16(Bw + (size_t)(col0 + r) * 3072 + kt * 64 + kcs * 8,
                  ((__bf16*)sB) + chunk * 8);
    }
    __syncthreads();
#pragma unroll
    for (int ks = 0; ks < 2; ++ks) {
      const int chs = ((ks * 4 + kq) ^ (r16 & 7)) << 4;  // swizzled byte chunk
      bf16x8 av[4], bv[4];
#pragma unroll
      for (int i = 0; i < 4; ++i)
        av[i] = *(const bf16x8*)(((const char*)sA) +
                                 (wm * 64 + i * 16 + r16) * 128 + chs);
#pragma unroll
      for (int j = 0; j < 4; ++j)
        bv[j] = *(const bf16x8*)(((const char*)sB) +
                                 (wn * 64 + j * 16 + r16) * 128 + chs);
#pragma unroll
      for (int i = 0; i < 4; ++i)
#pragma unroll
        for (int j = 0; j < 4; ++j)
          acc[i][j] = __builtin_amdgcn_mfma_f32_16x16x32_bf16(av[i], bv[j],
                                                              acc[i][j], 0, 0, 0);
    }
  }

#pragma unroll
  for (int i = 0; i < 4; ++i)
#pragma unroll
    for (int j = 0; j < 4; ++j)
#pragma unroll
      for (int r = 0; r < 4; ++r) {
        int row = row0 + wm * 64 + i * 16 + kq * 4 + r;
        int col = col0 + wn * 64 + j * 16 + r16;
        atomicAdd(out + (size_t)row * 1024 + col, acc[i][j][r] * QS);
      }
}

// ---------------- launch ----------------

extern "C" void kernel_launch(void* const* d_in, const int* in_sizes, int n_in,
                              void* d_out, int out_size, void* d_ws, size_t ws_size,
                              hipStream_t stream) {
  const float* x = (const float*)d_in[0];
  const int* wg = (const int*)d_in[1];
  const int* wu = (const int*)d_in[2];
  const int* wd = (const int*)d_in[3];

  char* ws = (char*)d_ws;
  __bf16* xb  = (__bf16*)(ws);                          // 16,777,216 B
  __bf16* w1  = (__bf16*)(ws + 16777216);               // 12,582,912 B
  __bf16* wdb = (__bf16*)(ws + 16777216 + 12582912);    //  6,291,456 B
  __bf16* h   = (__bf16*)(ws + 35651584);               // 50,331,648 B

  // zero the accumulation target (harness poisons d_out before every launch)
  hipMemsetAsync(d_out, 0, (size_t)8192 * 1024 * sizeof(float), stream);

  k_conv_x<<<4096, 256, 0, stream>>>(x, xb, 1048576);
  k_conv_w1<<<3072, 256, 0, stream>>>(wg, wu, w1);
  k_conv_wd<<<1536, 256, 0, stream>>>(wd, wdb, 393216);

  k_gemm1_8p<<<dim3(24, 32), 512, 0, stream>>>(xb, w1, h);
  k_gemm2a<<<1024, 256, 0, stream>>>(h, wdb, (float*)d_out);
}

// Round 8
// 274.238 us; speedup vs baseline: 1.1942x; 1.1942x over previous
//
#include <hip/hip_runtime.h>
#include <hip/hip_bf16.h>

// SwiGLU MLP: out = (silu(x@wg^T * S) * (x@wu^T * S)) @ wd^T * S,  S = 1/127
// Round 8: kernel count 6 -> 3. (1) convs fused into one launch. (2) G1 kept
// byte-identical to round-7 (measured 119.3 us, sole instantiation).
// (3) G2 = 2-phase 128^2, NO split-K, direct f32 store (no partials/reduce/
// memset/atomics). XCD-chunked map: each XCD owns 16 y-bands x 4 x-cols ->
// its B-half (3.1 MB) is L2-resident; h re-reads hit LLC (written by G1).

typedef __attribute__((ext_vector_type(8))) __bf16 bf16x8;
typedef __attribute__((ext_vector_type(4))) float f32x4;

static constexpr float QS = 1.0f / 127.0f;

#define BAR()    asm volatile("s_barrier" ::: "memory")
#define VMCNT4() asm volatile("s_waitcnt vmcnt(4)" ::: "memory")
#define VMCNT0() asm volatile("s_waitcnt vmcnt(0)" ::: "memory")
#define LGKM8()  asm volatile("s_waitcnt lgkmcnt(8)" ::: "memory")
#define PRIO1()  __builtin_amdgcn_s_setprio(1)
#define PRIO0()  __builtin_amdgcn_s_setprio(0)

__device__ __forceinline__ void gload_lds16(const void* g, void* l) {
  __builtin_amdgcn_global_load_lds(
      (const __attribute__((address_space(1))) void*)g,
      (__attribute__((address_space(3))) void*)l,
      16, 0, 0);
}

// ---------------- fused conversion kernel (one launch) ----------------
// blocks [0,4096): x f32->bf16 ; [4096,7168): w1 interleave ; [7168,8704): wd
__global__ __launch_bounds__(256) void k_conv_all(const float* __restrict__ x,
                                                  __bf16* __restrict__ xb,
                                                  const int* __restrict__ wg,
                                                  const int* __restrict__ wu,
                                                  __bf16* __restrict__ w1,
                                                  const int* __restrict__ wdn,
                                                  __bf16* __restrict__ wdb) {
  int b = blockIdx.x;
  if (b < 4096) {
    int t = b * 256 + threadIdx.x;                 // 1,048,576 threads
    const float4* p = (const float4*)(x + (size_t)t * 8);
    float4 a = p[0], c = p[1];
    bf16x8 o;
    o[0] = (__bf16)a.x; o[1] = (__bf16)a.y; o[2] = (__bf16)a.z; o[3] = (__bf16)a.w;
    o[4] = (__bf16)c.x; o[5] = (__bf16)c.y; o[6] = (__bf16)c.z; o[7] = (__bf16)c.w;
    *(bf16x8*)(xb + (size_t)t * 8) = o;
  } else if (b < 7168) {
    int t = (b - 4096) * 256 + threadIdx.x;        // 786,432 threads
    int c8 = t & 127;
    int v = t >> 7;
    int bb = v >> 5, tt = v & 31;
    const int* src = (tt < 16) ? (wg + (size_t)(bb * 16 + tt) * 1024)
                               : (wu + (size_t)(bb * 16 + (tt & 15)) * 1024);
    const int4* p = (const int4*)(src + c8 * 8);
    int4 a = p[0], c = p[1];
    bf16x8 o;
    o[0] = (__bf16)(float)a.x; o[1] = (__bf16)(float)a.y;
    o[2] = (__bf16)(float)a.z; o[3] = (__bf16)(float)a.w;
    o[4] = (__bf16)(float)c.x; o[5] = (__bf16)(float)c.y;
    o[6] = (__bf16)(float)c.z; o[7] = (__bf16)(float)c.w;
    *(bf16x8*)(w1 + (size_t)v * 1024 + c8 * 8) = o;
  } else {
    int t = (b - 7168) * 256 + threadIdx.x;        // 393,216 threads
    const int4* p = (const int4*)(wdn + (size_t)t * 8);
    int4 a = p[0], c = p[1];
    bf16x8 o;
    o[0] = (__bf16)(float)a.x; o[1] = (__bf16)(float)a.y;
    o[2] = (__bf16)(float)a.z; o[3] = (__bf16)(float)a.w;
    o[4] = (__bf16)(float)c.x; o[5] = (__bf16)(float)c.y;
    o[6] = (__bf16)(float)c.z; o[7] = (__bf16)(float)c.w;
    *(bf16x8*)(wdb + (size_t)t * 8) = o;
  }
}

// -------- G1: 256x256 8-phase GEMM, SwiGLU fused (round-7 code, exact) ------

#define MFMA16(MG, NG)                                                         \
  _Pragma("unroll") for (int mi = 0; mi < 4; ++mi) {                           \
    _Pragma("unroll") for (int nj = 0; nj < 2; ++nj) {                         \
      acc[(MG)*4 + mi][(NG)*2 + nj] = __builtin_amdgcn_mfma_f32_16x16x32_bf16( \
          af[mi][0], bf[NG][nj][0], acc[(MG)*4 + mi][(NG)*2 + nj], 0, 0, 0);   \
      acc[(MG)*4 + mi][(NG)*2 + nj] = __builtin_amdgcn_mfma_f32_16x16x32_bf16( \
          af[mi][1], bf[NG][nj][1], acc[(MG)*4 + mi][(NG)*2 + nj], 0, 0, 0);   \
    }                                                                          \
  }

#define LDAF(MG)                                                               \
  _Pragma("unroll") for (int mi = 0; mi < 4; ++mi) {                           \
    af[mi][0] = *(const bf16x8*)(aL + ((MG)*64 + mi * 16 + r16) * 128 + s0);   \
    af[mi][1] = *(const bf16x8*)(aL + ((MG)*64 + mi * 16 + r16) * 128 + s1);   \
  }

#define LDBF(NG)                                                               \
  _Pragma("unroll") for (int nj = 0; nj < 2; ++nj) {                           \
    bf[NG][nj][0] = *(const bf16x8*)(bL + (bro + (NG)*32 + nj * 16) * 128 + s0); \
    bf[NG][nj][1] = *(const bf16x8*)(bL + (bro + (NG)*32 + nj * 16) * 128 + s1); \
  }

__global__ __launch_bounds__(512, 2) void k_gemm1_8p(const __bf16* __restrict__ A,
                                                     const __bf16* __restrict__ Bp,
                                                     __bf16* __restrict__ Out) {
  constexpr int LDAK = 1024, NT = 16, LDO = 3072;
  const int row0 = blockIdx.y * 256, col0 = blockIdx.x * 256;
  const int kz = 0;
  __shared__ __bf16 sA[2][2][128][64];   // [buf][half][row][k]
  __shared__ __bf16 sB[2][2][128][64];
  const int tid = threadIdx.x;           // 0..511
  const int lane = tid & 63;
  const int wid = tid >> 6;              // 0..7
  const int wm = wid >> 2, wn = wid & 3; // 2 x 4 waves
  const int r16 = lane & 15;
  const int kq = lane >> 4;

  auto STG = [&](__bf16* dst, const __bf16* src, int rbase, int kt) {
    int r0 = tid >> 3;
    int c0 = (tid & 7) ^ (r0 & 7);               // inverse T2 swizzle on src
    int r1 = 64 + r0;
    gload_lds16(src + (size_t)(rbase + r0) * LDAK + kt * 64 + c0 * 8,
                dst + tid * 8);
    gload_lds16(src + (size_t)(rbase + r1) * LDAK + kt * 64 + c0 * 8,
                dst + (512 + tid) * 8);
  };

  f32x4 acc[8][4] = {};

  // prologue: T0 complete + T1:{Bh0, Ah0}
  STG(&sA[0][0][0][0], A, row0, kz);
  STG(&sB[0][0][0][0], Bp, col0, kz);
  STG(&sA[0][1][0][0], A, row0 + 128, kz);
  STG(&sB[0][1][0][0], Bp, col0 + 128, kz);
  const int kt1 = kz + 1;
  STG(&sB[1][0][0][0], Bp, col0, kt1);
  STG(&sA[1][0][0][0], A, row0, kt1);
  VMCNT4();   // T0 landed; T1:{Bh0,Ah0} in flight
  BAR();

  for (int t = 0; t < NT; ++t) {
    const int c = t & 1;
    const char* aL = (const char*)&sA[c][wm][0][0];
    const char* bL = (const char*)&sB[c][wn >> 1][0][0];
    const int bro = (wn & 1) * 64 + r16;
    const int s0 = ((kq) ^ (r16 & 7)) << 4;
    const int s1 = ((4 + kq) ^ (r16 & 7)) << 4;
    const int k1 = kz + (t + 1 < NT ? t + 1 : NT - 1);
    const int k2 = kz + (t + 2 < NT ? t + 2 : NT - 1);
    bf16x8 af[4][2], bf[2][2][2];

    // ---- phase 1: q(0,0)
    LDAF(0);
    LDBF(0);
    LGKM8();                                      // 12 reads issued; pre-drain
    STG(&sA[c ^ 1][1][0][0], A, row0 + 128, k1);  // T+1 Ah1 (idle buf)
    BAR();
    PRIO1(); MFMA16(0, 0); PRIO0();
    BAR();
    // ---- phase 2: q(0,1)
    LDBF(1);
    STG(&sB[c ^ 1][1][0][0], Bp, col0 + 128, k1); // T+1 Bh1 (idle buf)
    BAR();
    PRIO1(); MFMA16(0, 1); PRIO0();
    BAR();
    // ---- phase 3: q(1,0)  — B regions of buf c dead (last read ph2)
    LDAF(1);
    STG(&sB[c][0][0][0], Bp, col0, k2);           // T+2 Bh0
    BAR();
    PRIO1(); MFMA16(1, 0); PRIO0();
    BAR();
    // ---- phase 4: q(1,1)  — A regions of buf c dead (last read ph3)
    STG(&sA[c][0][0][0], A, row0, k2);            // T+2 Ah0
    BAR();
    PRIO1(); MFMA16(1, 1); PRIO0();
    VMCNT4();   // tile T+1 fully landed; 2 half-tiles stay in flight
    BAR();
  }

  // SwiGLU epilogue: B cols are (gate|up) 16-blocks -> gate/up of one h column
  // sit in adjacent j-fragments of the SAME lane.
  __bf16* hout = Out;
  const int hbase = (col0 + wn * 64) >> 1;
#pragma unroll
  for (int i = 0; i < 8; ++i) {
#pragma unroll
    for (int p = 0; p < 2; ++p) {
#pragma unroll
      for (int rr = 0; rr < 4; ++rr) {
        int row = row0 + wm * 128 + i * 16 + kq * 4 + rr;
        float g = acc[i][2 * p][rr] * QS;
        float u = acc[i][2 * p + 1][rr] * QS;
        float hv = (g / (1.0f + __expf(-g))) * u;
        hout[(size_t)row * LDO + hbase + p * 16 + r16] = (__bf16)hv;
      }
    }
  }
  VMCNT0();   // drain dead tail stages before LDS handoff to next block
}

// -------- G2: 2-phase 128^2, no split-K, direct f32 out ---------------------
// [8192,3072] x [1024,3072]^T -> out f32 [8192,1024]. 512 blocks = 2/CU.
// XCD map: xcd=b&7; XCD owns y in [(xcd&3)*16,+16), x in [(xcd>>2)*4,+4):
// B chunk 3.1 MB (L2-fit), h re-reads within XCD hit L2/LLC.
__global__ __launch_bounds__(256) void k_gemm2b(const __bf16* __restrict__ H,
                                                const __bf16* __restrict__ Bw,
                                                float* __restrict__ out) {
  __shared__ __bf16 sA[128][64];
  __shared__ __bf16 sB[128][64];
  const int b = blockIdx.x;
  const int xcd = b & 7, ii = b >> 3;          // ii 0..63
  const int yl = ii >> 2, xl = ii & 3;
  const int row0 = ((xcd & 3) * 16 + yl) * 128;
  const int col0 = ((xcd >> 2) * 4 + xl) * 128;

  const int tid = threadIdx.x;
  const int lane = tid & 63;
  const int wid = tid >> 6;
  const int wm = wid >> 1, wn = wid & 1;
  const int r16 = lane & 15;
  const int kq = lane >> 4;

  f32x4 acc[4][4] = {};

  for (int kt = 0; kt < 48; ++kt) {
    __syncthreads();
#pragma unroll
    for (int it = 0; it < 4; ++it) {
      int chunk = it * 256 + tid;  // 0..1023 chunks of 16B
      int r = chunk >> 3, kc = chunk & 7;
      int kcs = kc ^ (r & 7);  // inverse swizzle on the global source
      gload_lds16(H + (size_t)(row0 + r) * 3072 + kt * 64 + kcs * 8,
                  ((__bf16*)sA) + chunk * 8);
      gload_lds16(Bw + (size_t)(col0 + r) * 3072 + kt * 64 + kcs * 8,
                  ((__bf16*)sB) + chunk * 8);
    }
    __syncthreads();
#pragma unroll
    for (int ks = 0; ks < 2; ++ks) {
      const int chs = ((ks * 4 + kq) ^ (r16 & 7)) << 4;  // swizzled byte chunk
      bf16x8 av[4], bv[4];
#pragma unroll
      for (int i = 0; i < 4; ++i)
        av[i] = *(const bf16x8*)(((const char*)sA) +
                                 (wm * 64 + i * 16 + r16) * 128 + chs);
#pragma unroll
      for (int j = 0; j < 4; ++j)
        bv[j] = *(const bf16x8*)(((const char*)sB) +
                                 (wn * 64 + j * 16 + r16) * 128 + chs);
#pragma unroll
      for (int i = 0; i < 4; ++i)
#pragma unroll
        for (int j = 0; j < 4; ++j)
          acc[i][j] = __builtin_amdgcn_mfma_f32_16x16x32_bf16(av[i], bv[j],
                                                              acc[i][j], 0, 0, 0);
    }
  }

#pragma unroll
  for (int i = 0; i < 4; ++i)
#pragma unroll
    for (int j = 0; j < 4; ++j)
#pragma unroll
      for (int r = 0; r < 4; ++r) {
        int row = row0 + wm * 64 + i * 16 + kq * 4 + r;
        int col = col0 + wn * 64 + j * 16 + r16;
        out[(size_t)row * 1024 + col] = acc[i][j][r] * QS;
      }
}

// ---------------- launch ----------------

extern "C" void kernel_launch(void* const* d_in, const int* in_sizes, int n_in,
                              void* d_out, int out_size, void* d_ws, size_t ws_size,
                              hipStream_t stream) {
  const float* x = (const float*)d_in[0];
  const int* wg = (const int*)d_in[1];
  const int* wu = (const int*)d_in[2];
  const int* wd = (const int*)d_in[3];

  char* ws = (char*)d_ws;
  __bf16* xb  = (__bf16*)(ws);                          // 16,777,216 B
  __bf16* w1  = (__bf16*)(ws + 16777216);               // 12,582,912 B
  __bf16* wdb = (__bf16*)(ws + 16777216 + 12582912);    //  6,291,456 B
  __bf16* h   = (__bf16*)(ws + 35651584);               // 50,331,648 B

  k_conv_all<<<8704, 256, 0, stream>>>(x, xb, wg, wu, w1, wd, wdb);
  k_gemm1_8p<<<dim3(24, 32), 512, 0, stream>>>(xb, w1, h);
  k_gemm2b<<<512, 256, 0, stream>>>(h, wdb, (float*)d_out);
}